// Round 17
// baseline (54.336 us; speedup 1.0000x reference)
//
#include <hip/hip_runtime.h>

typedef _Float16 f16;
typedef _Float16 f16x4 __attribute__((ext_vector_type(4)));
typedef _Float16 f16x8 __attribute__((ext_vector_type(8)));
typedef __fp16 fp16x2 __attribute__((ext_vector_type(2)));   // cvt_pkrtz native type
typedef float f32x4 __attribute__((ext_vector_type(4)));

#define MFMA_16x16x32_F16(A, B, C) __builtin_amdgcn_mfma_f32_16x16x32_f16((A), (B), (C), 0, 0, 0)

typedef const __attribute__((address_space(1))) char gchar;
typedef __attribute__((address_space(3))) char lchar;

__device__ __forceinline__ float fexp2(float x) { return __builtin_amdgcn_exp2f(x); }
__device__ __forceinline__ int swzb(int b) { return b ^ ((b >> 3) & 0x70); }  // K-tile involution

namespace {
constexpr int SB = 4096;                       // tokens per flattened batch = 128 granules of 32
constexpr size_t BB = (size_t)SB * 64 * 2;     // f16 bytes per batch per tensor = 512KB
}

// V-ONLY token permutation within each 32-token granule (K stays identity!):
//   V^T granule slot n = 8g+4a+v holds token 16a+4g+v (a in {0,1}).
//   PV's K=32 B-fragment slot 8g+j then needs exactly the lane's own QK^T output
//   e[mt=a][v], so P never leaves registers.
// V granule layout: [64 dims][4 units of 16B], unit swizzled: unit' = unit ^ (d&3)
//   (2-bit swizzle keeps granules self-contained; read applies same XOR).

// ---------------- pre-pass: gather + fp16 convert + V granule-transpose ----------------
__global__ __launch_bounds__(256)
void hilbert_prepass_kernel(const float* __restrict__ kp, const float* __restrict__ vp,
                            const int* __restrict__ perm,
                            char* __restrict__ kw, char* __restrict__ vtw)
{
    const int bid = blockIdx.x;
    const int batch = bid & 7;
    const int tile = bid >> 3;
    const int tid = (int)threadIdx.x;
    const int r = tid >> 2;       // token in tile
    const int c4 = tid & 3;       // 16-dim quarter

    __shared__ float Vl[64][68];  // fp32 V tile, padded

    const int t = tile * 64 + r;
    const int srow = perm[batch * 512 + (t >> 3)];
    const size_t boff = (size_t)srow * 512 + (t & 7) * 64 + c4 * 16;

    {   // K -> fp16, IDENTITY row placement, swizzled store (8KB tiles, row-closed)
        const float* ks = kp + boff;
        const float4 k0 = *(const float4*)(ks + 0);
        const float4 k1 = *(const float4*)(ks + 4);
        const float4 k2 = *(const float4*)(ks + 8);
        const float4 k3 = *(const float4*)(ks + 12);
        f16x8 h0, h1;
        h0[0] = (f16)k0.x; h0[1] = (f16)k0.y; h0[2] = (f16)k0.z; h0[3] = (f16)k0.w;
        h0[4] = (f16)k1.x; h0[5] = (f16)k1.y; h0[6] = (f16)k1.z; h0[7] = (f16)k1.w;
        h1[0] = (f16)k2.x; h1[1] = (f16)k2.y; h1[2] = (f16)k2.z; h1[3] = (f16)k2.w;
        h1[4] = (f16)k3.x; h1[5] = (f16)k3.y; h1[6] = (f16)k3.z; h1[7] = (f16)k3.w;
        char* kt = kw + (size_t)batch * BB + (size_t)tile * 8192;
        const int o = r * 128 + c4 * 32;
        *(f16x8*)(kt + swzb(o)) = h0;
        *(f16x8*)(kt + swzb(o + 16)) = h1;
    }
    {   // V fp32 -> LDS
        const float* vs = vp + boff;
        *(float4*)&Vl[r][c4 * 16 + 0]  = *(const float4*)(vs + 0);
        *(float4*)&Vl[r][c4 * 16 + 4]  = *(const float4*)(vs + 4);
        *(float4*)&Vl[r][c4 * 16 + 8]  = *(const float4*)(vs + 8);
        *(float4*)&Vl[r][c4 * 16 + 12] = *(const float4*)(vs + 12);
    }
    __syncthreads();
    {   // transpose out of LDS: thread owns dim d, tokens 16a..16a+15 -> granule a>>1
        const int d = tid >> 2;
        const int a = tid & 3;
        char* vg = vtw + (size_t)batch * BB + ((size_t)tile * 2 + (a >> 1)) * 4096;
        const int half8 = (a & 1) * 8;     // byte offset of the 4-token run within its unit
#pragma unroll
        for (int gp = 0; gp < 4; ++gp) {   // slot unit gp holds tokens 16a+4gp+v
            f16x4 qv;
#pragma unroll
            for (int v = 0; v < 4; ++v) qv[v] = (f16)Vl[16 * a + 4 * gp + v][d];
            *(f16x4*)(vg + d * 64 + ((gp ^ (d & 3)) << 4) + half8) = qv;
        }
    }
}

// ---------------- main attention ----------------
// 256 blocks (1/CU) x 512 threads = 8 waves = (wq in {0,1}) x (quarter Kq in 0..3).
// Wave owns 64 q-rows (4 x 16-row subtiles sharing every K/V fragment read) and
// streams its CONTIGUOUS key quarter as 32 granules of 32 tokens.
// BARRIER-FREE main loop: each wave stages into its PRIVATE 16KB LDS region
// (dbuf 2 x {K 4KB | V 4KB}) via global_load_lds, synced only by its own
// counted s_waitcnt vmcnt(8) — waves drift into anti-phase, overlapping
// MFMA / VALU / LDS / VMEM pipes (the r9-r16 block-wide barriers phase-locked
// all waves into the same phase; this isolates that hypothesis).
// NO-MAX softmax; P in registers (V-kappa layout per 32-granule).
// LDS 128KB: 8 waves x 16KB; reused as merge scratch after the loop.
__global__ __launch_bounds__(512, 2)
void hilbert_attn_kernel(const float* __restrict__ qp,
                         const int* __restrict__ perm,
                         const char* __restrict__ kw, const char* __restrict__ vtw,
                         float* __restrict__ op)
{
    __shared__ __align__(16) char SM[131072];

    const int bid = blockIdx.x;
    const int batch = bid & 7;            // XCD-affine: one batch per XCD
    const int qbase = (bid >> 3) * 128;
    const int tid = (int)threadIdx.x;
    const int w = tid >> 6;
    const int lane = tid & 63;
    const int l16 = lane & 15;
    const int g = lane >> 4;
    const int Kq = w >> 1;                // key quarter (1024 contiguous keys)
    const int wq = w & 1;                 // q 64-row slot

    // Q B-fragments for four 16-row slots; scale*log2e folded
    f16x8 Qf[4][2];
    {
        constexpr float qscl = 0.125f * 1.44269504088896340736f;
#pragma unroll
        for (int s = 0; s < 4; ++s) {
            const int t = qbase + wq * 64 + s * 16 + l16;
            const int srow = perm[batch * 512 + (t >> 3)];
            const float* src = qp + (size_t)srow * 512 + (t & 7) * 64 + g * 8;
#pragma unroll
            for (int kt = 0; kt < 2; ++kt) {
                const float4 x0 = *(const float4*)(src + 32 * kt);
                const float4 x1 = *(const float4*)(src + 32 * kt + 4);
                f16x8 f;
                f[0] = (f16)(x0.x * qscl); f[1] = (f16)(x0.y * qscl);
                f[2] = (f16)(x0.z * qscl); f[3] = (f16)(x0.w * qscl);
                f[4] = (f16)(x1.x * qscl); f[5] = (f16)(x1.y * qscl);
                f[6] = (f16)(x1.z * qscl); f[7] = (f16)(x1.w * qscl);
                Qf[s][kt] = f;
            }
        }
    }

    f32x4 oacc[4][4];
#pragma unroll
    for (int s = 0; s < 4; ++s)
#pragma unroll
        for (int i = 0; i < 4; ++i) oacc[s][i] = (f32x4){0.f, 0.f, 0.f, 0.f};
    float lr[4] = {0.f, 0.f, 0.f, 0.f};

    const char* kbase = kw + (size_t)batch * BB;    // granule gr: (gr>>1)*8192 + (gr&1)*4096
    const char* vbase = vtw + (size_t)batch * BB;   // granule gr: gr*4096
    const int gr0 = Kq * 32;
    lchar* myL = (lchar*)&SM[w * 16384];            // private: [2 bufs][K 4KB | V 4KB]

    union U8 { f16x8 v; fp16x2 h[4]; };

#define STAGE_GR(buf, gr)                                                            \
    do {                                                                             \
        lchar* dst_ = myL + (buf) * 8192;                                            \
        const char* ks_ = kbase + ((gr) >> 1) * 8192 + ((gr) & 1) * 4096 + lane * 16;\
        const char* vs_ = vbase + (size_t)(gr) * 4096 + lane * 16;                   \
        __builtin_amdgcn_global_load_lds((gchar*)(ks_ + 0),    dst_ + 0,    16, 0, 0);\
        __builtin_amdgcn_global_load_lds((gchar*)(ks_ + 1024), dst_ + 1024, 16, 0, 0);\
        __builtin_amdgcn_global_load_lds((gchar*)(ks_ + 2048), dst_ + 2048, 16, 0, 0);\
        __builtin_amdgcn_global_load_lds((gchar*)(ks_ + 3072), dst_ + 3072, 16, 0, 0);\
        __builtin_amdgcn_global_load_lds((gchar*)(vs_ + 0),    dst_ + 4096, 16, 0, 0);\
        __builtin_amdgcn_global_load_lds((gchar*)(vs_ + 1024), dst_ + 5120, 16, 0, 0);\
        __builtin_amdgcn_global_load_lds((gchar*)(vs_ + 2048), dst_ + 6144, 16, 0, 0);\
        __builtin_amdgcn_global_load_lds((gchar*)(vs_ + 3072), dst_ + 7168, 16, 0, 0);\
    } while (0)

    STAGE_GR(0, gr0);
    asm volatile("s_waitcnt vmcnt(0)" ::: "memory");

    for (int it = 0; it < 32; ++it) {
        const int buf = it & 1;
        if (it < 31) {
            STAGE_GR(buf ^ 1, gr0 + it + 1);
            asm volatile("s_waitcnt vmcnt(8)" ::: "memory");   // own cur-buffer loads done
        } else {
            asm volatile("s_waitcnt vmcnt(0)" ::: "memory");
        }
        const char* Kl = (const char*)&SM[w * 16384 + buf * 8192];

        // ---- fragment reads (private LDS, no cross-wave hazard) ----
        f16x8 kf[4], vf[4];
#pragma unroll
        for (int kt = 0; kt < 2; ++kt)
#pragma unroll
            for (int mt = 0; mt < 2; ++mt) {
                const int off = (l16 + 16 * mt) * 128 + (((g + 4 * kt) * 16) ^ ((l16 & 7) << 4));
                kf[kt * 2 + mt] = *(const f16x8*)&Kl[off];
            }
#pragma unroll
        for (int mtd = 0; mtd < 4; ++mtd) {
            const int voff = 4096 + (l16 + 16 * mtd) * 64 + ((g ^ (l16 & 3)) << 4);
            vf[mtd] = *(const f16x8*)&Kl[voff];
        }

        // ---- S^T = K * Q^T (4 q-slots share each K fragment) ----
        f32x4 sa[4][2];
#pragma unroll
        for (int s = 0; s < 4; ++s)
#pragma unroll
            for (int mt = 0; mt < 2; ++mt) sa[s][mt] = (f32x4){0.f, 0.f, 0.f, 0.f};
        __builtin_amdgcn_s_setprio(1);
#pragma unroll
        for (int kt = 0; kt < 2; ++kt)
#pragma unroll
            for (int mt = 0; mt < 2; ++mt)
#pragma unroll
                for (int s = 0; s < 4; ++s)
                    sa[s][mt] = MFMA_16x16x32_F16(kf[kt * 2 + mt], Qf[s][kt], sa[s][mt]);
        __builtin_amdgcn_s_setprio(0);

        // ---- no-max softmax, P packed to registers (V-kappa per-32 layout) ----
        U8 P[4];
#pragma unroll
        for (int s = 0; s < 4; ++s) {
#pragma unroll
            for (int mt = 0; mt < 2; ++mt) {
                const float a0 = fexp2(sa[s][mt][0]);
                const float a1 = fexp2(sa[s][mt][1]);
                const float a2 = fexp2(sa[s][mt][2]);
                const float a3 = fexp2(sa[s][mt][3]);
                lr[s] += (a0 + a1) + (a2 + a3);
                P[s].h[2 * mt]     = __builtin_amdgcn_cvt_pkrtz(a0, a1);
                P[s].h[2 * mt + 1] = __builtin_amdgcn_cvt_pkrtz(a2, a3);
            }
        }

        // ---- O^T += V^T * P^T (one K=32 step; 4 slots share each V fragment) ----
        __builtin_amdgcn_s_setprio(1);
#pragma unroll
        for (int mtd = 0; mtd < 4; ++mtd)
#pragma unroll
            for (int s = 0; s < 4; ++s)
                oacc[s][mtd] = MFMA_16x16x32_F16(vf[mtd], P[s].v, oacc[s][mtd]);
        __builtin_amdgcn_s_setprio(0);
    }
#undef STAGE_GR

    // ---- reduce l across the 4 key-groups of each wave ----
#pragma unroll
    for (int s = 0; s < 4; ++s) {
        lr[s] += __shfl_xor(lr[s], 16);
        lr[s] += __shfl_xor(lr[s], 32);
    }

    __syncthreads();   // first block-wide sync since loop start; reuse SM for merge

    // ---- merge across 4 key-quarters: Kq=1,2,3 dump partials, Kq=0 combines ----
    float* OB = (float*)SM;                 // 6 regions x 16KB (64 rows x 64 dims)
    float* ML = (float*)&SM[98304];         // 6 regions x 64 l-values
    if (Kq >= 1) {
        float* ob = OB + ((Kq - 1) * 2 + wq) * 4096;
#pragma unroll
        for (int s = 0; s < 4; ++s)
#pragma unroll
            for (int mtd = 0; mtd < 4; ++mtd)
                *(f32x4*)&ob[(s * 16 + l16) * 64 + mtd * 16 + g * 4] = oacc[s][mtd];
        if (g == 0)
#pragma unroll
            for (int s = 0; s < 4; ++s)
                ML[((Kq - 1) * 2 + wq) * 64 + s * 16 + l16] = lr[s];
    }
    __syncthreads();
    if (Kq == 0) {
#pragma unroll
        for (int s = 0; s < 4; ++s) {
            float lsum = lr[s];
#pragma unroll
            for (int p = 0; p < 3; ++p) lsum += ML[(p * 2 + wq) * 64 + s * 16 + l16];
            const float linv = 1.f / lsum;
            const int t = qbase + wq * 64 + s * 16 + l16;
            const int srow = perm[t];       // scatter uses FULL-t perm (round-1 lesson)
            float* dst = op + (size_t)srow * 512 + batch * 64 + 4 * g;
#pragma unroll
            for (int mtd = 0; mtd < 4; ++mtd) {
                f32x4 acc = oacc[s][mtd];
#pragma unroll
                for (int p = 0; p < 3; ++p) {
                    const f32x4 o2 = *(const f32x4*)&OB[(p * 2 + wq) * 4096 +
                                                        (s * 16 + l16) * 64 + mtd * 16 + g * 4];
                    acc[0] += o2[0]; acc[1] += o2[1]; acc[2] += o2[2]; acc[3] += o2[3];
                }
                float4 o;
                o.x = acc[0] * linv; o.y = acc[1] * linv;
                o.z = acc[2] * linv; o.w = acc[3] * linv;
                *(float4*)(dst + 16 * mtd) = o;
            }
        }
    }
}

extern "C" void kernel_launch(void* const* d_in, const int* in_sizes, int n_in,
                              void* d_out, int out_size, void* d_ws, size_t ws_size,
                              hipStream_t stream) {
    (void)in_sizes; (void)n_in; (void)out_size; (void)ws_size;
    const float* q = (const float*)d_in[0];
    const float* k = (const float*)d_in[1];
    const float* v = (const float*)d_in[2];
    const int* perm = (const int*)d_in[3];
    float* out = (float*)d_out;
    char* kw = (char*)d_ws;          // 4MB
    char* vtw = kw + 8 * BB;         // 4MB
    hipLaunchKernelGGL(hilbert_prepass_kernel, dim3(512), dim3(256), 0, stream,
                       k, v, perm, kw, vtw);
    hipLaunchKernelGGL(hilbert_attn_kernel, dim3(256), dim3(512), 0, stream,
                       q, perm, kw, vtw, out);
}

// Round 18
// 52.501 us; speedup vs baseline: 1.0349x; 1.0349x over previous
//
#include <hip/hip_runtime.h>

typedef _Float16 f16;
typedef _Float16 f16x4 __attribute__((ext_vector_type(4)));
typedef _Float16 f16x8 __attribute__((ext_vector_type(8)));
typedef __fp16 fp16x2 __attribute__((ext_vector_type(2)));   // cvt_pkrtz native type
typedef float f32x4 __attribute__((ext_vector_type(4)));

#define MFMA_16x16x32_F16(A, B, C) __builtin_amdgcn_mfma_f32_16x16x32_f16((A), (B), (C), 0, 0, 0)

typedef const __attribute__((address_space(1))) char gchar;
typedef __attribute__((address_space(3))) char lchar;

__device__ __forceinline__ float fexp2(float x) { return __builtin_amdgcn_exp2f(x); }
__device__ __forceinline__ int swzb(int b) { return b ^ ((b >> 3) & 0x70); }  // involution, 8KB-tile-local

namespace {
constexpr int SB = 4096;                       // tokens per flattened batch = 64 tiles of 64
constexpr size_t BB = (size_t)SB * 64 * 2;     // f16 bytes per batch per tensor = 512KB
}

// V-ONLY token permutation within each 64-token tile (K stays identity!):
//   V^T stored slot n holds token kappa_V(n), kappa_V(32kt+8g+4a+v)=32kt+16a+4g+v.
//   PV's B-fragment slot 32kt+8g+j then needs exactly the lane's own QK^T output
//   e[8kt+j], so P never leaves registers.
__device__ __forceinline__ int kinv(int r) {
    return 32 * (r >> 5) + 8 * ((r >> 2) & 3) + 4 * ((r >> 4) & 1) + (r & 3);
}

// ---------------- pre-pass: gather + fp16 convert + V tile-transpose ----------------
// Stores PRE-SWIZZLED within each 8KB tile; V additionally kappa_V-permuted in token axis.
__global__ __launch_bounds__(256)
void hilbert_prepass_kernel(const float* __restrict__ kp, const float* __restrict__ vp,
                            const int* __restrict__ perm,
                            char* __restrict__ kw, char* __restrict__ vtw)
{
    const int bid = blockIdx.x;
    const int batch = bid & 7;
    const int tile = bid >> 3;
    const int tid = (int)threadIdx.x;
    const int r = tid >> 2;       // token in tile
    const int c4 = tid & 3;       // 16-dim quarter

    __shared__ float Vl[64][68];  // fp32 V tile, padded

    const int t = tile * 64 + r;
    const int srow = perm[batch * 512 + (t >> 3)];
    const size_t boff = (size_t)srow * 512 + (t & 7) * 64 + c4 * 16;

    {   // K -> fp16, IDENTITY row placement, swizzled store
        const float* ks = kp + boff;
        const float4 k0 = *(const float4*)(ks + 0);
        const float4 k1 = *(const float4*)(ks + 4);
        const float4 k2 = *(const float4*)(ks + 8);
        const float4 k3 = *(const float4*)(ks + 12);
        f16x8 h0, h1;
        h0[0] = (f16)k0.x; h0[1] = (f16)k0.y; h0[2] = (f16)k0.z; h0[3] = (f16)k0.w;
        h0[4] = (f16)k1.x; h0[5] = (f16)k1.y; h0[6] = (f16)k1.z; h0[7] = (f16)k1.w;
        h1[0] = (f16)k2.x; h1[1] = (f16)k2.y; h1[2] = (f16)k2.z; h1[3] = (f16)k2.w;
        h1[4] = (f16)k3.x; h1[5] = (f16)k3.y; h1[6] = (f16)k3.z; h1[7] = (f16)k3.w;
        char* kt = kw + (size_t)batch * BB + (size_t)tile * 8192;
        const int o = r * 128 + c4 * 32;
        *(f16x8*)(kt + swzb(o)) = h0;
        *(f16x8*)(kt + swzb(o + 16)) = h1;
    }
    {   // V fp32 -> LDS
        const float* vs = vp + boff;
        *(float4*)&Vl[r][c4 * 16 + 0]  = *(const float4*)(vs + 0);
        *(float4*)&Vl[r][c4 * 16 + 4]  = *(const float4*)(vs + 4);
        *(float4*)&Vl[r][c4 * 16 + 8]  = *(const float4*)(vs + 8);
        *(float4*)&Vl[r][c4 * 16 + 12] = *(const float4*)(vs + 12);
    }
    __syncthreads();
    {   // transpose out of LDS: thread owns dim d, tokens 16a..16a+15; kappa_V cols
        const int d = tid >> 2;
        const int a = tid & 3;
        char* vt = vtw + (size_t)batch * BB + (size_t)tile * 8192;
        const int b0 = 32 * (a >> 1) + 4 * (a & 1);
#pragma unroll
        for (int gp = 0; gp < 4; ++gp) {
            f16x4 qv;
#pragma unroll
            for (int v = 0; v < 4; ++v) qv[v] = (f16)Vl[16 * a + 4 * gp + v][d];
            *(f16x4*)(vt + swzb(d * 128 + (b0 + 8 * gp) * 2)) = qv;
        }
    }
}

// ---------------- main attention ----------------
// 256 blocks (1/CU) x 512 threads = 8 waves = wq(4) x half(2); wave owns 32 q-rows
// (two 16-row subtiles sharing every K/V fragment read); half takes tiles 2m+half.
// T15 SOFTWARE-PIPELINED BODY (phase-shifted by one granule):
//   body(n): stage K(n+2) -> [vmcnt(4)+barA: V(n),K(n+1) confirmed] ->
//            QK(n+1) (MFMA, ->sn) || exp2(sa(n)) (VALU, indep!) -> PV(n) (MFMA)
//            -> [barB] -> stage V(n+2) -> sp=sn.
// Every inter-barrier segment mixes 32 MFMA + full softmax VALU with no
// cross-dependency -> intra-wave pipe overlap (r9-r17 bodies were serial
// QK->exp2->PV; this is the untested lever). NO-MAX softmax; P in regs.
// LDS (64KB): buf[2] x {K-pair 16KB | V-pair 16KB}; K(m),V(m) live in buf[m&1].
__global__ __launch_bounds__(512, 2)
void hilbert_attn_kernel(const float* __restrict__ qp,
                         const int* __restrict__ perm,
                         const char* __restrict__ kw, const char* __restrict__ vtw,
                         float* __restrict__ op)
{
    __shared__ __align__(16) char SM[65536];

    const int bid = blockIdx.x;
    const int batch = bid & 7;            // XCD-affine: one batch per XCD
    const int qbase = (bid >> 3) * 128;
    const int tid = (int)threadIdx.x;
    const int w = tid >> 6;
    const int lane = tid & 63;
    const int l16 = lane & 15;
    const int g = lane >> 4;
    const int half = w >> 2;
    const int wq = w & 3;
    const int swz = (l16 & 7) << 4;

    // Q B-fragments for both 16-row slots; scale*log2e folded
    f16x8 Qf0[2], Qf1[2];
    {
        constexpr float qscl = 0.125f * 1.44269504088896340736f;
#pragma unroll
        for (int s = 0; s < 2; ++s) {
            const int t = qbase + wq * 32 + s * 16 + l16;
            const int srow = perm[batch * 512 + (t >> 3)];
            const float* src = qp + (size_t)srow * 512 + (t & 7) * 64 + g * 8;
#pragma unroll
            for (int kt = 0; kt < 2; ++kt) {
                const float4 x0 = *(const float4*)(src + 32 * kt);
                const float4 x1 = *(const float4*)(src + 32 * kt + 4);
                f16x8 f;
                f[0] = (f16)(x0.x * qscl); f[1] = (f16)(x0.y * qscl);
                f[2] = (f16)(x0.z * qscl); f[3] = (f16)(x0.w * qscl);
                f[4] = (f16)(x1.x * qscl); f[5] = (f16)(x1.y * qscl);
                f[6] = (f16)(x1.z * qscl); f[7] = (f16)(x1.w * qscl);
                if (s == 0) Qf0[kt] = f; else Qf1[kt] = f;
            }
        }
    }

    f32x4 oacc0[4], oacc1[4];
#pragma unroll
    for (int i = 0; i < 4; ++i) {
        oacc0[i] = (f32x4){0.f, 0.f, 0.f, 0.f};
        oacc1[i] = (f32x4){0.f, 0.f, 0.f, 0.f};
    }
    float lr0 = 0.f, lr1 = 0.f;

    const char* ksrc = kw + (size_t)batch * BB + (size_t)tid * 16;
    const char* vsrc = vtw + (size_t)batch * BB + (size_t)tid * 16;

    union U8 { f16x8 v; fp16x2 h[4]; };

#define STAGE_K(dstbuf, p)                                                           \
    do {                                                                             \
        lchar* d_ = (lchar*)&SM[(dstbuf) * 32768 + (w << 10)];                       \
        const char* s_ = ksrc + (size_t)(p) * 16384;                                 \
        __builtin_amdgcn_global_load_lds((gchar*)(s_), d_, 16, 0, 0);                \
        __builtin_amdgcn_global_load_lds((gchar*)(s_ + 8192), d_ + 8192, 16, 0, 0);  \
    } while (0)
#define STAGE_V(dstbuf, p)                                                           \
    do {                                                                             \
        lchar* d_ = (lchar*)&SM[(dstbuf) * 32768 + 16384 + (w << 10)];               \
        const char* s_ = vsrc + (size_t)(p) * 16384;                                 \
        __builtin_amdgcn_global_load_lds((gchar*)(s_), d_, 16, 0, 0);                \
        __builtin_amdgcn_global_load_lds((gchar*)(s_ + 8192), d_ + 8192, 16, 0, 0);  \
    } while (0)

    // prologue: K0,V0 -> buf0; K1 -> buf1; confirm K0,V0; QK(0); then V1 -> buf1
    STAGE_K(0, 0);
    STAGE_V(0, 0);
    STAGE_K(1, 1);
    asm volatile("s_waitcnt vmcnt(2)" ::: "memory");   // K0,V0 confirmed; K1 in flight
    __builtin_amdgcn_s_barrier();

    f32x4 sp0[4], sp1[4];   // scores of granule n (persist across body)
#pragma unroll
    for (int i = 0; i < 4; ++i) {
        sp0[i] = (f32x4){0.f, 0.f, 0.f, 0.f};
        sp1[i] = (f32x4){0.f, 0.f, 0.f, 0.f};
    }
    {   // QK(0) from buf0
        const int kbb = half * 8192;
#pragma unroll
        for (int kt = 0; kt < 2; ++kt) {
#pragma unroll
            for (int mt = 0; mt < 4; ++mt) {
                const int off = kbb + (l16 + 16 * mt) * 128 + (((g + 4 * kt) * 16) ^ swz);
                const f16x8 kf = *(const f16x8*)&SM[off];
                sp0[mt] = MFMA_16x16x32_F16(kf, Qf0[kt], sp0[mt]);
                sp1[mt] = MFMA_16x16x32_F16(kf, Qf1[kt], sp1[mt]);
            }
        }
    }
    __builtin_amdgcn_s_barrier();   // all waves done reading K0 (body0 restages buf0.K)
    STAGE_V(1, 1);

    for (int n = 0; n < 31; ++n) {
        const int cur = n & 1, nxt = cur ^ 1;
        const int p2 = (n + 2 > 31) ? 31 : n + 2;   // clamped: dup-stage keeps counts uniform

        // stage K(n+2) -> buf[cur].K  (K(n) dead since last body's barB)
        STAGE_K(cur, p2);

        // barA: confirms {V(n), K(n+1)}; leaves {V(n+1), K(n+2)} in flight
        asm volatile("s_waitcnt vmcnt(4)" ::: "memory");
        __builtin_amdgcn_s_barrier();

        // ---- QK(n+1) from buf[nxt].K -> sn (MFMA; independent of exp2 below) ----
        f32x4 sn0[4], sn1[4];
#pragma unroll
        for (int i = 0; i < 4; ++i) {
            sn0[i] = (f32x4){0.f, 0.f, 0.f, 0.f};
            sn1[i] = (f32x4){0.f, 0.f, 0.f, 0.f};
        }
        {
            const int kbb = nxt * 32768 + half * 8192;
            __builtin_amdgcn_s_setprio(1);
#pragma unroll
            for (int kt = 0; kt < 2; ++kt) {
#pragma unroll
                for (int mt = 0; mt < 4; ++mt) {
                    const int off = kbb + (l16 + 16 * mt) * 128 + (((g + 4 * kt) * 16) ^ swz);
                    const f16x8 kf = *(const f16x8*)&SM[off];
                    sn0[mt] = MFMA_16x16x32_F16(kf, Qf0[kt], sn0[mt]);
                    sn1[mt] = MFMA_16x16x32_F16(kf, Qf1[kt], sn1[mt]);
                }
            }
            __builtin_amdgcn_s_setprio(0);
        }

        // ---- exp2/pack of sa(n) (VALU; a full body of slack since QK(n) issued) ----
        U8 p0k0, p0k1, p1k0, p1k1;
#pragma unroll
        for (int mt = 0; mt < 4; ++mt) {
            const float a0 = fexp2(sp0[mt][0]);
            const float a1 = fexp2(sp0[mt][1]);
            const float a2 = fexp2(sp0[mt][2]);
            const float a3 = fexp2(sp0[mt][3]);
            lr0 += (a0 + a1) + (a2 + a3);
            const float b0 = fexp2(sp1[mt][0]);
            const float b1 = fexp2(sp1[mt][1]);
            const float b2 = fexp2(sp1[mt][2]);
            const float b3 = fexp2(sp1[mt][3]);
            lr1 += (b0 + b1) + (b2 + b3);
            if (mt < 2) {
                p0k0.h[2 * mt]     = __builtin_amdgcn_cvt_pkrtz(a0, a1);
                p0k0.h[2 * mt + 1] = __builtin_amdgcn_cvt_pkrtz(a2, a3);
                p1k0.h[2 * mt]     = __builtin_amdgcn_cvt_pkrtz(b0, b1);
                p1k0.h[2 * mt + 1] = __builtin_amdgcn_cvt_pkrtz(b2, b3);
            } else {
                p0k1.h[2 * (mt - 2)]     = __builtin_amdgcn_cvt_pkrtz(a0, a1);
                p0k1.h[2 * (mt - 2) + 1] = __builtin_amdgcn_cvt_pkrtz(a2, a3);
                p1k1.h[2 * (mt - 2)]     = __builtin_amdgcn_cvt_pkrtz(b0, b1);
                p1k1.h[2 * (mt - 2) + 1] = __builtin_amdgcn_cvt_pkrtz(b2, b3);
            }
        }

        // ---- PV(n) from buf[cur].V ----
        {
            const int vbb = cur * 32768 + 16384 + half * 8192;
            __builtin_amdgcn_s_setprio(1);
#pragma unroll
            for (int kt = 0; kt < 2; ++kt) {
                const f16x8 pf0 = kt ? p0k1.v : p0k0.v;
                const f16x8 pf1 = kt ? p1k1.v : p1k0.v;
#pragma unroll
                for (int mtd = 0; mtd < 4; ++mtd) {
                    const int voff = vbb + (l16 + 16 * mtd) * 128 + (((g + 4 * kt) * 16) ^ swz);
                    const f16x8 vf = *(const f16x8*)&SM[voff];
                    oacc0[mtd] = MFMA_16x16x32_F16(vf, pf0, oacc0[mtd]);
                    oacc1[mtd] = MFMA_16x16x32_F16(vf, pf1, oacc1[mtd]);
                }
            }
            __builtin_amdgcn_s_setprio(0);
        }

        // barB: all waves past K(n+1)/V(n) reads -> their halves may be restaged
        __builtin_amdgcn_s_barrier();
        STAGE_V(cur, p2);   // V(n+2) -> buf[cur].V (V(n) dead)

        // shift pipeline: sp = sn (static copies, no scratch)
#pragma unroll
        for (int i = 0; i < 4; ++i) { sp0[i] = sn0[i]; sp1[i] = sn1[i]; }
    }

    // ---- tail: granule 31 (scores in sp; V(31) in buf[1].V) ----
    asm volatile("s_waitcnt vmcnt(0)" ::: "memory");   // drain dup stages before SM reuse
    __builtin_amdgcn_s_barrier();
    {
        U8 p0k0, p0k1, p1k0, p1k1;
#pragma unroll
        for (int mt = 0; mt < 4; ++mt) {
            const float a0 = fexp2(sp0[mt][0]);
            const float a1 = fexp2(sp0[mt][1]);
            const float a2 = fexp2(sp0[mt][2]);
            const float a3 = fexp2(sp0[mt][3]);
            lr0 += (a0 + a1) + (a2 + a3);
            const float b0 = fexp2(sp1[mt][0]);
            const float b1 = fexp2(sp1[mt][1]);
            const float b2 = fexp2(sp1[mt][2]);
            const float b3 = fexp2(sp1[mt][3]);
            lr1 += (b0 + b1) + (b2 + b3);
            if (mt < 2) {
                p0k0.h[2 * mt]     = __builtin_amdgcn_cvt_pkrtz(a0, a1);
                p0k0.h[2 * mt + 1] = __builtin_amdgcn_cvt_pkrtz(a2, a3);
                p1k0.h[2 * mt]     = __builtin_amdgcn_cvt_pkrtz(b0, b1);
                p1k0.h[2 * mt + 1] = __builtin_amdgcn_cvt_pkrtz(b2, b3);
            } else {
                p0k1.h[2 * (mt - 2)]     = __builtin_amdgcn_cvt_pkrtz(a0, a1);
                p0k1.h[2 * (mt - 2) + 1] = __builtin_amdgcn_cvt_pkrtz(a2, a3);
                p1k1.h[2 * (mt - 2)]     = __builtin_amdgcn_cvt_pkrtz(b0, b1);
                p1k1.h[2 * (mt - 2) + 1] = __builtin_amdgcn_cvt_pkrtz(b2, b3);
            }
        }
        const int vbb = 32768 + 16384 + half * 8192;
#pragma unroll
        for (int kt = 0; kt < 2; ++kt) {
            const f16x8 pf0 = kt ? p0k1.v : p0k0.v;
            const f16x8 pf1 = kt ? p1k1.v : p1k0.v;
#pragma unroll
            for (int mtd = 0; mtd < 4; ++mtd) {
                const int voff = vbb + (l16 + 16 * mtd) * 128 + (((g + 4 * kt) * 16) ^ swz);
                const f16x8 vf = *(const f16x8*)&SM[voff];
                oacc0[mtd] = MFMA_16x16x32_F16(vf, pf0, oacc0[mtd]);
                oacc1[mtd] = MFMA_16x16x32_F16(vf, pf1, oacc1[mtd]);
            }
        }
    }
#undef STAGE_K
#undef STAGE_V

    // ---- reduce l across the 4 key-groups of each wave ----
    lr0 += __shfl_xor(lr0, 16);
    lr0 += __shfl_xor(lr0, 32);
    lr1 += __shfl_xor(lr1, 16);
    lr1 += __shfl_xor(lr1, 32);

    __syncthreads();   // loop done; reuse SM for merge

    // ---- merge wave pairs (w, w+4): l = la+lb, O = Oa+Ob ----
    float* OB = (float*)SM;                 // 4 pairs x 8KB (32 rows x 64 dims)
    float* ML = (float*)&SM[32768];         // 4 pairs x 32 l-values
    if (w >= 4) {
        float* ob = OB + wq * 2048;
#pragma unroll
        for (int mtd = 0; mtd < 4; ++mtd) {
            *(f32x4*)&ob[l16 * 64 + mtd * 16 + g * 4] = oacc0[mtd];
            *(f32x4*)&ob[(16 + l16) * 64 + mtd * 16 + g * 4] = oacc1[mtd];
        }
        if (g == 0) {
            ML[wq * 32 + l16] = lr0;
            ML[wq * 32 + 16 + l16] = lr1;
        }
    }
    __syncthreads();
    if (w < 4) {
        float* ob = OB + wq * 2048;
#pragma unroll
        for (int s = 0; s < 2; ++s) {
            const float lmine = (s == 0) ? lr0 : lr1;
            const float linv = 1.f / (lmine + ML[wq * 32 + s * 16 + l16]);
            const int t = qbase + wq * 32 + s * 16 + l16;
            const int srow = perm[t];       // scatter uses FULL-t perm (round-1 lesson)
            float* dst = op + (size_t)srow * 512 + batch * 64 + 4 * g;
#pragma unroll
            for (int mtd = 0; mtd < 4; ++mtd) {
                const f32x4 mine = (s == 0) ? oacc0[mtd] : oacc1[mtd];
                const f32x4 o2 = *(const f32x4*)&ob[(s * 16 + l16) * 64 + mtd * 16 + g * 4];
                float4 o;
                o.x = (mine[0] + o2[0]) * linv;
                o.y = (mine[1] + o2[1]) * linv;
                o.z = (mine[2] + o2[2]) * linv;
                o.w = (mine[3] + o2[3]) * linv;
                *(float4*)(dst + 16 * mtd) = o;
            }
        }
    }
}

extern "C" void kernel_launch(void* const* d_in, const int* in_sizes, int n_in,
                              void* d_out, int out_size, void* d_ws, size_t ws_size,
                              hipStream_t stream) {
    (void)in_sizes; (void)n_in; (void)out_size; (void)ws_size;
    const float* q = (const float*)d_in[0];
    const float* k = (const float*)d_in[1];
    const float* v = (const float*)d_in[2];
    const int* perm = (const int*)d_in[3];
    float* out = (float*)d_out;
    char* kw = (char*)d_ws;          // 4MB
    char* vtw = kw + 8 * BB;         // 4MB
    hipLaunchKernelGGL(hilbert_prepass_kernel, dim3(512), dim3(256), 0, stream,
                       k, v, perm, kw, vtw);
    hipLaunchKernelGGL(hilbert_attn_kernel, dim3(256), dim3(512), 0, stream,
                       q, perm, kw, vtw, out);
}